// Round 10
// baseline (622.177 us; speedup 1.0000x reference)
//
#include <hip/hip_runtime.h>

// ---------------------------------------------------------------------------
// multi_head_attention: B=2, S=2048, E=1024, H=16, HD=64, fp32 in/out.
// bf16 MFMA (16x16x32) everywhere, fp32 accumulate.
// R1-R11: swizzles, permuted-key P/V, XCD-locality (K/V L2-resident).
// R12-R15: attn ladder -> R14 best (512thr, 16 q-rows/wave, dbuf, 1 barrier/
//     tile, 47.5us). R13 lesson: only global_load_lds+barrier survives hipcc.
// R16-R19: four structural gemm changes (64t->128t, 1->2-phase, occupancy
//     1->2->3 blk/CU, BK64->32) -> non-attn INVARIANT at 132-140us while
//     BW-floor math says cvt+qkv+out ~ 25-35us. Hypothesis: per-kernel
//     launch overhead ~10-15us dominates; gemms never visible in top-5.
// R20: FUSE 4 kernels -> 2 persistent kernels with in-kernel grid barriers.
//     cvt_qkv (768x256): cvt grid-strided -> barrier(768) -> R19 qkv body.
//     attn_out (512x512): R14 attn -> barrier(512) -> gemm_out at 512thr
//     (same 128x64 tiles, 8 waves 32x32, acc[2][2]; swizzles unchanged).
//     Barrier counters alias memory written only AFTER use (ctr1=Cb[0:4],
//     ctr2=out[0:4]); zeroed per-iteration by two 4B hipMemsetAsync nodes.
//     Residency guaranteed: launch_bounds (256,3) -> 3 blk/CU * 256 = 768;
//     (512,4) -> 2 blk/CU * 256 = 512. Cross-XCD visibility: __threadfence
//     (agent scope = buffer_wbl2/inv on gfx950) both sides + device-scope
//     atomic arrive. Diagnostic: top-5 finally shows both fused kernels ->
//     per-phase budget revealed. Predict total -> ~165 if overhead real.
// ---------------------------------------------------------------------------

typedef __bf16 bf16x8 __attribute__((ext_vector_type(8)));
typedef __bf16 bf16x4 __attribute__((ext_vector_type(4)));
typedef float f32x4 __attribute__((ext_vector_type(4)));
typedef unsigned short ushort_t;

#define S_LEN 2048
#define E_DIM 1024
#define H_NUM 16
#define HD_DIM 64

#if __has_builtin(__builtin_amdgcn_exp2f)
#define EXP2(x) __builtin_amdgcn_exp2f(x)
#else
#define EXP2(x) __exp2f(x)
#endif

__device__ __forceinline__ ushort_t f2bf(float f) {
  union { float f; unsigned u; } v; v.f = f;
  unsigned u = v.u;
  unsigned r = (u + 0x7FFFu + ((u >> 16) & 1u)) >> 16;  // RNE
  return (ushort_t)r;
}

#define GLDS16(gp, lp)                                              \
  __builtin_amdgcn_global_load_lds(                                 \
      (const __attribute__((address_space(1))) unsigned int*)(gp),  \
      (__attribute__((address_space(3))) unsigned int*)(lp), 16, 0, 0)

// Grid ticket barrier. ctr zeroed per-iteration by host memset; every block
// arrives once; all blocks spin until count == N. Fences make prior stores
// device-visible (agent release = buffer_wbl2) and later loads fresh
// (acquire = buffer_inv). Requires all N blocks co-resident.
__device__ __forceinline__ void grid_barrier(unsigned* ctr, unsigned N,
                                             int t) {
  __threadfence();
  __syncthreads();
  if (t == 0) {
    __hip_atomic_fetch_add(ctr, 1u, __ATOMIC_ACQ_REL,
                           __HIP_MEMORY_SCOPE_AGENT);
    while (__hip_atomic_load(ctr, __ATOMIC_ACQUIRE,
                             __HIP_MEMORY_SCOPE_AGENT) < N)
      __builtin_amdgcn_s_sleep(8);
  }
  __syncthreads();
  __threadfence();
}

// ---------------- fused cvt + QKV projection gemm --------------------------
// Phase 1: fp32->bf16 converts, grid-strided over 768 blocks.
// Phase 2 (after barrier): R19 qkv body: BK=32 2-phase dbuf, 3 blocks/CU.
// A = Xbf [4096][1024], B = Wqkv [3][1024][1024]; XCD swizzle 8m x 12n.

#define GQ_STEP(KT, Ac, Bc, An, Bn, DOPRE)                                    \
  {                                                                           \
    if (DOPRE) {                                                              \
      GLDS16(Ag0 + (size_t)((KT) + 1) * 32, (An) + t * 8);                    \
      GLDS16(Ag1 + (size_t)((KT) + 1) * 32, (An) + 2048 + t * 8);             \
      GLDS16(Bg0 + (size_t)((KT) + 1) * 32, (Bn) + t * 8);                    \
      GLDS16(Bg1 + (size_t)((KT) + 1) * 32, (Bn) + 2048 + t * 8);             \
    }                                                                         \
    bf16x8 af[4], bfr[4];                                                     \
    const int gs = quad ^ ((lr >> 1) & 3);                                    \
    _Pragma("unroll") for (int i = 0; i < 4; i++) {                           \
      af[i]  = *(const bf16x8*)((Ac) + (wm + i * 16 + lr) * 32 + gs * 8);     \
      bfr[i] = *(const bf16x8*)((Bc) + (wn + i * 16 + lr) * 32 + gs * 8);     \
    }                                                                         \
    if (matid < 2) {                                                          \
      _Pragma("unroll") for (int i = 0; i < 4; i++)                           \
        _Pragma("unroll") for (int j = 0; j < 4; j++)                         \
          acc[i][j] = __builtin_amdgcn_mfma_f32_16x16x32_bf16(                \
              bfr[j], af[i], acc[i][j], 0, 0, 0); /* C^T */                   \
    } else {                                                                  \
      _Pragma("unroll") for (int i = 0; i < 4; i++)                           \
        _Pragma("unroll") for (int j = 0; j < 4; j++)                         \
          acc[i][j] = __builtin_amdgcn_mfma_f32_16x16x32_bf16(                \
              af[i], bfr[j], acc[i][j], 0, 0, 0);                             \
    }                                                                         \
    __syncthreads();                                                          \
  }

__global__ __launch_bounds__(256, 3) void cvt_qkv(
    const float* __restrict__ X, const float* __restrict__ Wq,
    const float* __restrict__ Wk, const float* __restrict__ Wv,
    const float* __restrict__ Wo, ushort_t* __restrict__ Xbf,
    ushort_t* __restrict__ Wqkv, ushort_t* __restrict__ Wob,
    const float* __restrict__ bq, const float* __restrict__ bk,
    const float* __restrict__ bv, ushort_t* __restrict__ Qb,
    ushort_t* __restrict__ Kb, ushort_t* __restrict__ Vt,
    unsigned* __restrict__ ctr1) {
  __shared__ ushort_t smem[16384];  // As0|Bs0|As1|Bs1; reused as C tile (Ls)
  const int t = threadIdx.x;
  const int bid = blockIdx.x;

  // ---- phase 1: converts (2,097,152 float4 items over 768 blocks) ----
  for (int k = 0; k < 11; ++k) {
    int i = k * 196608 + bid * 256 + t;
    if (i < 2097152) {
      const float* src;
      ushort_t* dst;
      int off;
      if (i < 1048576) {
        src = X; dst = Xbf; off = i;
      } else if (i < 1310720) {
        src = Wq; dst = Wqkv; off = i - 1048576;
      } else if (i < 1572864) {
        src = Wk; dst = Wqkv + (1 << 20); off = i - 1310720;
      } else if (i < 1835008) {
        src = Wv; dst = Wqkv + (2 << 20); off = i - 1572864;
      } else {
        src = Wo; dst = Wob; off = i - 1835008;
      }
      float4 v = ((const float4*)src)[off];
      ushort4 o;
      o.x = f2bf(v.x); o.y = f2bf(v.y); o.z = f2bf(v.z); o.w = f2bf(v.w);
      ((ushort4*)dst)[off] = o;
    }
  }

  grid_barrier(ctr1, 768u, t);

  // ---- phase 2: QKV gemm (R19 body verbatim) ----
  ushort_t* As0 = smem;
  ushort_t* Bs0 = smem + 4096;
  ushort_t* As1 = smem + 8192;
  ushort_t* Bs1 = smem + 12288;
  const int w = t >> 6, lane = t & 63, quad = lane >> 4, lr = lane & 15;
  const int k8 = bid & 7, u = bid >> 3;  // u in [0,96)
  const int m0 = ((k8 >> 1) * 8 + (u & 7)) * 128;   // m-tile in [0,32)
  const int n0 = ((k8 & 1) * 12 + (u >> 3)) * 128;  // n-tile in [0,24)
  const int wm = (w & 1) * 64, wn = (w >> 1) * 64;
  const int matid = n0 >> 10;
  const int nl0 = n0 & 1023;

  const int srow4 = t >> 2;
  const int gsrc4 = (t & 3) ^ ((t >> 3) & 3);
  const ushort_t* Ag0 = Xbf + (size_t)(m0 + srow4) * E_DIM + gsrc4 * 8;
  const ushort_t* Ag1 = Xbf + (size_t)(m0 + 64 + srow4) * E_DIM + gsrc4 * 8;
  const ushort_t* Bg0 = Wqkv + (size_t)matid * E_DIM * E_DIM +
                        (size_t)(nl0 + srow4) * E_DIM + gsrc4 * 8;
  const ushort_t* Bg1 = Wqkv + (size_t)matid * E_DIM * E_DIM +
                        (size_t)(nl0 + 64 + srow4) * E_DIM + gsrc4 * 8;

  f32x4 acc[4][4] = {};

  GLDS16(Ag0, As0 + t * 8);
  GLDS16(Ag1, As0 + 2048 + t * 8);
  GLDS16(Bg0, Bs0 + t * 8);
  GLDS16(Bg1, Bs0 + 2048 + t * 8);
  __syncthreads();

  for (int kt = 0; kt < E_DIM / 32; kt += 2) {
    GQ_STEP(kt, As0, Bs0, As1, Bs1, 1);
    GQ_STEP(kt + 1, As1, Bs1, As0, Bs0, (kt < E_DIM / 32 - 2));
  }

  const float* bias_p = (matid == 0) ? bq : (matid == 1) ? bk : bv;
  ushort_t* Ls = smem;
  if (matid < 2) {
    ushort_t* dst = (matid == 0) ? Qb : Kb;
    const float scl = (matid == 0) ? 0.18033688f : 1.0f;  // 0.125*log2e
#pragma unroll
    for (int j = 0; j < 4; j++) {
      const int nb = wn + j * 16 + quad * 4;
      float b0 = bias_p[nl0 + nb], b1 = bias_p[nl0 + nb + 1];
      float b2 = bias_p[nl0 + nb + 2], b3 = bias_p[nl0 + nb + 3];
#pragma unroll
      for (int i = 0; i < 4; i++) {
        const int m = wm + i * 16 + lr;
        bf16x4 pv;
        pv[0] = (__bf16)((acc[i][j][0] + b0) * scl);
        pv[1] = (__bf16)((acc[i][j][1] + b1) * scl);
        pv[2] = (__bf16)((acc[i][j][2] + b2) * scl);
        pv[3] = (__bf16)((acc[i][j][3] + b3) * scl);
        *(bf16x4*)(Ls + m * 128 + (((nb >> 3) ^ (m & 7)) * 8) + (nb & 7)) = pv;
      }
    }
    __syncthreads();
#pragma unroll
    for (int it = 0; it < 8; it++) {
      const int task = t + 256 * it;
      const int m = task >> 4, g = task & 15;
      uint4 val = *(const uint4*)(Ls + m * 128 + ((g ^ (m & 7)) * 8));
      const int s = m0 + m, bb = s >> 11, ss = s & 2047;
      const int cl = nl0 + g * 8, h = cl >> 6, dd = cl & 63;
      *(uint4*)(dst + ((size_t)((bb * H_NUM + h) * S_LEN + ss)) * HD_DIM + dd) =
          val;
    }
  } else {
#pragma unroll
    for (int j = 0; j < 4; j++) {
      const int n = wn + j * 16 + lr;
      const float bias = bias_p[nl0 + n];
#pragma unroll
      for (int i = 0; i < 4; i++) {
        const int mb = wm + i * 16 + quad * 4;
        bf16x4 pv;
        pv[0] = (__bf16)(acc[i][j][0] + bias);
        pv[1] = (__bf16)(acc[i][j][1] + bias);
        pv[2] = (__bf16)(acc[i][j][2] + bias);
        pv[3] = (__bf16)(acc[i][j][3] + bias);
        *(bf16x4*)(Ls + n * 128 + (((mb >> 3) ^ (n & 7)) * 8) + (mb & 7)) = pv;
      }
    }
    __syncthreads();
    const int n = t & 127, grp2 = t >> 7;
    ushort_t v[64];
#pragma unroll
    for (int c = 0; c < 8; c++)
      *(uint4*)(v + c * 8) =
          *(const uint4*)(Ls + n * 128 + (((grp2 * 8 + c) ^ (n & 7)) * 8));
    const int cl = nl0 + n, h = cl >> 6, dd = cl & 63;
    const int sgb = m0 + grp2 * 64, bb = sgb >> 11, ssb = sgb & 2047;
    ushort_t* dstp =
        Vt + ((size_t)((bb * H_NUM + h) * HD_DIM + dd)) * S_LEN + ssb;
#pragma unroll
    for (int q = 0; q < 8; q++) {
      ushort_t o8[8];
#pragma unroll
      for (int u2 = 0; u2 < 8; u2++)
        o8[u2] = v[16 * (u2 & 3) + 2 * q + (u2 >> 2)];
      *(uint4*)(dstp + q * 8) = *(const uint4*)o8;
    }
  }
}

// ---------------- fused flash attention + output gemm ----------------------
// Phase 1: R14 attn verbatim (8 waves, dbuf K/V, 1 barrier/tile).
// Phase 2 (after barrier): gemm_out 128x64 tiles at 512 threads: 8 waves of
// 32x32 (wm=(w&3)*32, wn=(w>>2)*32, acc[2][2]); 2-phase dbuf; same swizzles.

#define ATTN_STEP(KT, Kc, Vc, Kn, Vn)                                         \
  {                                                                           \
    const int kn = ((KT) + 1) & (S_LEN / 64 - 1);                             \
    GLDS16(Kg + (size_t)(kn * 64 + srow) * HD_DIM + gsrc * 8, (Kn) + t * 8);  \
    GLDS16(Vg + (size_t)srow * S_LEN + kn * 64 + gsrc * 8, (Vn) + t * 8);     \
    f32x4 sacc[4] = {};                                                       \
    __builtin_amdgcn_s_setprio(1);                                            \
    _Pragma("unroll") for (int nt = 0; nt < 4; nt++) {                        \
      _Pragma("unroll") for (int kc = 0; kc < 2; kc++) {                      \
        const int gs = (kc * 4 + quad) ^ (lr & 7);                            \
        bf16x8 kf = *(const bf16x8*)((Kc) + (nt * 16 + lr) * 64 + gs * 8);    \
        sacc[nt] = __builtin_amdgcn_mfma_f32_16x16x32_bf16(                   \
            qf[kc], kf, sacc[nt], 0, 0, 0);                                   \
      }                                                                       \
    }                                                                         \
    __builtin_amdgcn_s_setprio(0);                                            \
    _Pragma("unroll") for (int i = 0; i < 4; i++) {                           \
      float p0 = EXP2(sacc[0][i]);                                            \
      float p1 = EXP2(sacc[1][i]);                                            \
      float p2 = EXP2(sacc[2][i]);                                            \
      float p3 = EXP2(sacc[3][i]);                                            \
      bf16x4 pv;                                                              \
      pv[0] = (__bf16)p0; pv[1] = (__bf16)p1;                                 \
      pv[2] = (__bf16)p2; pv[3] = (__bf16)p3;                                 \
      const int prow = w * 16 + quad * 4 + i;                                 \
      *(bf16x4*)(Ps + prow * 72 + lr * 4) = pv;                               \
    }                                                                         \
    __builtin_amdgcn_s_setprio(1);                                            \
    _Pragma("unroll") for (int kc = 0; kc < 2; kc++) {                        \
      const int gs = (kc * 4 + quad) ^ (lr & 7);                              \
      bf16x8 vf[4];                                                           \
      _Pragma("unroll") for (int dt = 0; dt < 4; dt++)                        \
        vf[dt] = *(const bf16x8*)((Vc) + (dt * 16 + lr) * 64 + gs * 8);       \
      bf16x8 pf = *(const bf16x8*)(Ps + (w * 16 + lr) * 72 +                  \
                                   kc * 32 + quad * 8);                       \
      lsum = __builtin_amdgcn_mfma_f32_16x16x32_bf16(                         \
          pf, ones, lsum, 0, 0, 0);                                           \
      _Pragma("unroll") for (int dt = 0; dt < 4; dt++)                        \
        cacc[dt] = __builtin_amdgcn_mfma_f32_16x16x32_bf16(                   \
            pf, vf[dt], cacc[dt], 0, 0, 0);                                   \
    }                                                                         \
    __builtin_amdgcn_s_setprio(0);                                            \
    __syncthreads();                                                          \
  }

#define GO_STEP(KT, Ac, Bc, An, Bn, DOPRE)                                    \
  {                                                                           \
    if (DOPRE) {                                                              \
      _Pragma("unroll") for (int r = 0; r < 2; r++)                           \
        GLDS16(Agb + (size_t)((KT) + 1) * 64 + (size_t)r * 64 * E_DIM,        \
               (An) + r * 4096 + t * 8);                                      \
      GLDS16(Bgb + (size_t)((KT) + 1) * 64, (Bn) + t * 8);                    \
    }                                                                         \
    _Pragma("unroll") for (int kk = 0; kk < 2; kk++) {                        \
      bf16x8 af[2], bfr[2];                                                   \
      const int gs0 = (kk * 4 + quad) ^ (lr & 7);                             \
      _Pragma("unroll") for (int i = 0; i < 2; i++)                           \
        af[i]  = *(const bf16x8*)((Ac) + (wm + i * 16 + lr) * 64 + gs0 * 8);  \
      _Pragma("unroll") for (int j = 0; j < 2; j++)                           \
        bfr[j] = *(const bf16x8*)((Bc) + (wn + j * 16 + lr) * 64 + gs0 * 8);  \
      _Pragma("unroll") for (int i = 0; i < 2; i++)                           \
        _Pragma("unroll") for (int j = 0; j < 2; j++)                         \
          acc[i][j] = __builtin_amdgcn_mfma_f32_16x16x32_bf16(                \
              af[i], bfr[j], acc[i][j], 0, 0, 0);                             \
    }                                                                         \
    __syncthreads();                                                          \
  }

__global__ __launch_bounds__(512, 4) void attn_out(
    const ushort_t* __restrict__ Qb, const ushort_t* __restrict__ Kb,
    const ushort_t* __restrict__ Vt, ushort_t* __restrict__ Ctx,
    const ushort_t* __restrict__ Wob, const float* __restrict__ bo,
    float* __restrict__ out, unsigned* __restrict__ ctr2) {
  __shared__ ushort_t smem[25600];  // 50KB; attn carve, reused by out phase
  const int t = threadIdx.x, w = t >> 6, lane = t & 63;
  const int quad = lane >> 4, lr = lane & 15;
  const int bid = blockIdx.x;

  // ---- phase 1: attn (R14 verbatim; Ks/Vs/Ps carved from smem) ----
  {
    ushort_t* Ks0 = smem;             // 4096 ushorts
    ushort_t* Ks1 = smem + 4096;
    ushort_t* Vs0 = smem + 8192;
    ushort_t* Vs1 = smem + 12288;
    ushort_t* Ps  = smem + 16384;     // 9216 ushorts (128 x 72)

    const int bh = (bid >> 7) * 8 + (bid & 7);     // [0,32)
    const int q0 = ((bid >> 3) & 15) * 128;
    const ushort_t* Qg = Qb + ((size_t)bh * S_LEN + q0) * HD_DIM;
    const ushort_t* Kg = Kb + (size_t)bh * S_LEN * HD_DIM;
    const ushort_t* Vg = Vt + (size_t)bh * HD_DIM * S_LEN;

    const int srow = t >> 3;                // staging LDS row in [0,64)
    const int gsrc = (t & 7) ^ (srow & 7);  // swizzled source granule

#pragma unroll
    for (int r = 0; r < 2; r++)
      GLDS16(Qg + (size_t)(r * 64 + srow) * HD_DIM + gsrc * 8,
             Ps + r * 4096 + t * 8);
    GLDS16(Kg + (size_t)srow * HD_DIM + gsrc * 8, Ks0 + t * 8);
    GLDS16(Vg + (size_t)srow * S_LEN + gsrc * 8, Vs0 + t * 8);
    __syncthreads();
    bf16x8 qf[2];  // [kc]; wave-private rows [16w, 16w+16)
#pragma unroll
    for (int kc = 0; kc < 2; kc++) {
      int gs = (kc * 4 + quad) ^ (lr & 7);
      qf[kc] = *(const bf16x8*)(Ps + (w * 16 + lr) * 64 + gs * 8);
    }
    __syncthreads();  // all waves own qf before Ps reused for P rows

    bf16x8 ones;
#pragma unroll
    for (int e = 0; e < 8; e++) ones[e] = (__bf16)1.0f;

    f32x4 cacc[4] = {};
    f32x4 lsum = {};

    for (int kt = 0; kt < S_LEN / 64; kt += 2) {
      ATTN_STEP(kt, Ks0, Vs0, Ks1, Vs1);
      ATTN_STEP(kt + 1, Ks1, Vs1, Ks0, Vs0);
    }

#pragma unroll
    for (int i = 0; i < 4; i++) {
      float inv = 1.0f / lsum[i];
      int srow2 = q0 + w * 16 + quad * 4 + i;
#pragma unroll
      for (int dt = 0; dt < 4; dt++)
        Ctx[((size_t)bh * S_LEN + srow2) * HD_DIM + dt * 16 + lr] =
            f2bf(cacc[dt][i] * inv);
    }
  }

  grid_barrier(ctr2, 512u, t);

  // ---- phase 2: output gemm, 128x64 tiles, 512 threads, 2-phase dbuf ----
  {
    ushort_t* As0 = smem;             // 8192 ushorts (128x64)
    ushort_t* Bs0 = smem + 8192;      // 4096 ushorts (64x64)
    ushort_t* As1 = smem + 12288;
    ushort_t* Bs1 = smem + 20480;     // ends 24576 <= 25600

    const int k8 = bid & 7, u = bid >> 3;     // u in [0,64)
    const int m0 = (k8 * 4 + (u & 3)) * 128;  // m-tile in [0,32)
    const int n0 = (u >> 2) * 64;             // n-tile in [0,16)
    const int wm = (w & 3) * 32, wn = (w >> 2) * 32;  // 8 waves: 4m x 2n

    const int srow = t >> 3;                // [0,64): 64-row staging chunks
    const int gsrc = (t & 7) ^ (srow & 7);
    const ushort_t* Agb =
        (const ushort_t*)Ctx + (size_t)(m0 + srow) * E_DIM + gsrc * 8;
    const ushort_t* Bgb = Wob + (size_t)(n0 + srow) * E_DIM + gsrc * 8;

    f32x4 acc[2][2] = {};

    // prologue: stage kt=0 into buf0 (A: 2 passes of 64 rows; B: 1 pass)
#pragma unroll
    for (int r = 0; r < 2; r++)
      GLDS16(Agb + (size_t)r * 64 * E_DIM, As0 + r * 4096 + t * 8);
    GLDS16(Bgb, Bs0 + t * 8);
    __syncthreads();

    for (int kt = 0; kt < E_DIM / 64; kt += 2) {
      GO_STEP(kt, As0, Bs0, As1, Bs1, 1);
      GO_STEP(kt + 1, As1, Bs1, As0, Bs0, (kt < E_DIM / 64 - 2));
    }

    // acc[i][j]: row m = wm+i*16+quad*4+r, col n = wn+j*16+lr.
#pragma unroll
    for (int j = 0; j < 2; j++) {
      const int col = n0 + wn + j * 16 + lr;
      const float bias = bo[col];
#pragma unroll
      for (int i = 0; i < 2; i++) {
#pragma unroll
        for (int r = 0; r < 4; r++) {
          const int row = m0 + wm + i * 16 + quad * 4 + r;
          out[(size_t)row * E_DIM + col] = acc[i][j][r] + bias;
        }
      }
    }
  }
}

// ---------------- launch ----------------
extern "C" void kernel_launch(void* const* d_in, const int* in_sizes, int n_in,
                              void* d_out, int out_size, void* d_ws,
                              size_t ws_size, hipStream_t stream) {
  const float* X  = (const float*)d_in[0];
  const float* bq = (const float*)d_in[2];
  const float* bk = (const float*)d_in[4];
  const float* bv = (const float*)d_in[6];
  const float* Wo = (const float*)d_in[7];
  const float* bo = (const float*)d_in[8];
  float* out = (float*)d_out;

  char* ws = (char*)d_ws;
  ushort_t* Xbf  = (ushort_t*)(ws);                       // 8 MB
  ushort_t* Wqkv = (ushort_t*)(ws + ((size_t)8 << 20));   // 6 MB
  ushort_t* Wob  = (ushort_t*)(ws + ((size_t)14 << 20));  // 2 MB
  ushort_t* Qb   = (ushort_t*)(ws + ((size_t)16 << 20));  // 8 MB
  ushort_t* Kb   = (ushort_t*)(ws + ((size_t)24 << 20));  // 8 MB
  ushort_t* Vt   = (ushort_t*)(ws + ((size_t)32 << 20));  // 8 MB
  ushort_t* Cb   = (ushort_t*)(ws + ((size_t)40 << 20));  // 8 MB (48 MB total)

  // Barrier counters alias memory written only AFTER their barrier:
  // ctr1 = Cb[0:4) (attn overwrites Cb in the next kernel);
  // ctr2 = out[0:4) (gemm_out phase overwrites after its barrier).
  unsigned* ctr1 = (unsigned*)Cb;
  unsigned* ctr2 = (unsigned*)out;
  hipMemsetAsync(ctr1, 0, 4, stream);
  hipMemsetAsync(ctr2, 0, 4, stream);

  cvt_qkv<<<768, 256, 0, stream>>>(X, (const float*)d_in[1],
                                   (const float*)d_in[3],
                                   (const float*)d_in[5], Wo, Xbf, Wqkv, Wob,
                                   bq, bk, bv, Qb, Kb, Vt, ctr1);
  attn_out<<<512, 512, 0, stream>>>(Qb, Kb, Vt, Cb, Wob, bo, out, ctr2);
}

// Round 11
// 597.481 us; speedup vs baseline: 1.0413x; 1.0413x over previous
//
#include <hip/hip_runtime.h>

// ---------------------------------------------------------------------------
// multi_head_attention: B=2, S=2048, E=1024, H=16, HD=64, fp32 in/out.
// bf16 MFMA (16x16x32) everywhere, fp32 accumulate.
// R1-R11: swizzles, permuted-key P/V, XCD-locality (K/V L2-resident).
// R12-R15: attn ladder -> R14 best (512thr, 16 q-rows/wave, dbuf, 47.5us).
// R16-R19: four structural gemm changes -> non-attn INVARIANT 132-140us.
//     Hypothesis: per-kernel launch overhead dominates non-attn budget.
// R20: fused into 2 persistent kernels + grid barriers: REGRESSED 622us.
//     Diagnosis from counters: work unchanged (MfmaUtil%xdur == R14's MFMA
//     seconds), wall stretched 6x, FETCH flat -> the ACQUIRE-per-poll spin
//     emitted buffer_inv each iteration; 1280 spinning waves continuously
//     invalidated every XCD's L1/L2, demoting peers' L2-resident reads to
//     L3 (invisible to FETCH). Fusion concept NOT refuted - spin was.
// R21: identical structure; barrier protocol fixed: release fence once ->
//     RELAXED fetch_add -> RELAXED spin (no cache maintenance per poll;
//     relaxed agent atomics still reach the device coherence point, proven
//     by R20 passing) -> one acquire fence after exit. s_sleep(64) ~1.7us
//     poll. Pre-commit: attn_out >=150us -> revert fusion, declare R17.
// ---------------------------------------------------------------------------

typedef __bf16 bf16x8 __attribute__((ext_vector_type(8)));
typedef __bf16 bf16x4 __attribute__((ext_vector_type(4)));
typedef float f32x4 __attribute__((ext_vector_type(4)));
typedef unsigned short ushort_t;

#define S_LEN 2048
#define E_DIM 1024
#define H_NUM 16
#define HD_DIM 64

#if __has_builtin(__builtin_amdgcn_exp2f)
#define EXP2(x) __builtin_amdgcn_exp2f(x)
#else
#define EXP2(x) __exp2f(x)
#endif

__device__ __forceinline__ ushort_t f2bf(float f) {
  union { float f; unsigned u; } v; v.f = f;
  unsigned u = v.u;
  unsigned r = (u + 0x7FFFu + ((u >> 16) & 1u)) >> 16;  // RNE
  return (ushort_t)r;
}

#define GLDS16(gp, lp)                                              \
  __builtin_amdgcn_global_load_lds(                                 \
      (const __attribute__((address_space(1))) unsigned int*)(gp),  \
      (__attribute__((address_space(3))) unsigned int*)(lp), 16, 0, 0)

// Grid ticket barrier, R21 protocol. ctr zeroed per-iteration by host
// memset. Release fence ONCE before arrival (flush my stores to the device
// coherence point); RELAXED arrive + RELAXED spin (no per-poll cache
// maintenance -- this was R20's 6x regression); one acquire fence on exit.
// Requires all N blocks co-resident (guaranteed by __launch_bounds__).
__device__ __forceinline__ void grid_barrier(unsigned* ctr, unsigned N,
                                             int t) {
  __threadfence();  // release: wbL2 once
  __syncthreads();
  if (t == 0) {
    __hip_atomic_fetch_add(ctr, 1u, __ATOMIC_RELAXED,
                           __HIP_MEMORY_SCOPE_AGENT);
    while (__hip_atomic_load(ctr, __ATOMIC_RELAXED,
                             __HIP_MEMORY_SCOPE_AGENT) < N)
      __builtin_amdgcn_s_sleep(64);  // ~1.7us poll, no inv traffic
  }
  __syncthreads();
  __threadfence();  // acquire: inv once, now read peers' data fresh
}

// ---------------- fused cvt + QKV projection gemm --------------------------
// Phase 1: fp32->bf16 converts, grid-strided over 768 blocks.
// Phase 2 (after barrier): R19 qkv body: BK=32 2-phase dbuf, 3 blocks/CU.
// A = Xbf [4096][1024], B = Wqkv [3][1024][1024]; XCD swizzle 8m x 12n.

#define GQ_STEP(KT, Ac, Bc, An, Bn, DOPRE)                                    \
  {                                                                           \
    if (DOPRE) {                                                              \
      GLDS16(Ag0 + (size_t)((KT) + 1) * 32, (An) + t * 8);                    \
      GLDS16(Ag1 + (size_t)((KT) + 1) * 32, (An) + 2048 + t * 8);             \
      GLDS16(Bg0 + (size_t)((KT) + 1) * 32, (Bn) + t * 8);                    \
      GLDS16(Bg1 + (size_t)((KT) + 1) * 32, (Bn) + 2048 + t * 8);             \
    }                                                                         \
    bf16x8 af[4], bfr[4];                                                     \
    const int gs = quad ^ ((lr >> 1) & 3);                                    \
    _Pragma("unroll") for (int i = 0; i < 4; i++) {                           \
      af[i]  = *(const bf16x8*)((Ac) + (wm + i * 16 + lr) * 32 + gs * 8);     \
      bfr[i] = *(const bf16x8*)((Bc) + (wn + i * 16 + lr) * 32 + gs * 8);     \
    }                                                                         \
    if (matid < 2) {                                                          \
      _Pragma("unroll") for (int i = 0; i < 4; i++)                           \
        _Pragma("unroll") for (int j = 0; j < 4; j++)                         \
          acc[i][j] = __builtin_amdgcn_mfma_f32_16x16x32_bf16(                \
              bfr[j], af[i], acc[i][j], 0, 0, 0); /* C^T */                   \
    } else {                                                                  \
      _Pragma("unroll") for (int i = 0; i < 4; i++)                           \
        _Pragma("unroll") for (int j = 0; j < 4; j++)                         \
          acc[i][j] = __builtin_amdgcn_mfma_f32_16x16x32_bf16(                \
              af[i], bfr[j], acc[i][j], 0, 0, 0);                             \
    }                                                                         \
    __syncthreads();                                                          \
  }

__global__ __launch_bounds__(256, 3) void cvt_qkv(
    const float* __restrict__ X, const float* __restrict__ Wq,
    const float* __restrict__ Wk, const float* __restrict__ Wv,
    const float* __restrict__ Wo, ushort_t* __restrict__ Xbf,
    ushort_t* __restrict__ Wqkv, ushort_t* __restrict__ Wob,
    const float* __restrict__ bq, const float* __restrict__ bk,
    const float* __restrict__ bv, ushort_t* __restrict__ Qb,
    ushort_t* __restrict__ Kb, ushort_t* __restrict__ Vt,
    unsigned* __restrict__ ctr1) {
  __shared__ ushort_t smem[16384];  // As0|Bs0|As1|Bs1; reused as C tile (Ls)
  const int t = threadIdx.x;
  const int bid = blockIdx.x;

  // ---- phase 1: converts (2,097,152 float4 items over 768 blocks) ----
  for (int k = 0; k < 11; ++k) {
    int i = k * 196608 + bid * 256 + t;
    if (i < 2097152) {
      const float* src;
      ushort_t* dst;
      int off;
      if (i < 1048576) {
        src = X; dst = Xbf; off = i;
      } else if (i < 1310720) {
        src = Wq; dst = Wqkv; off = i - 1048576;
      } else if (i < 1572864) {
        src = Wk; dst = Wqkv + (1 << 20); off = i - 1310720;
      } else if (i < 1835008) {
        src = Wv; dst = Wqkv + (2 << 20); off = i - 1572864;
      } else {
        src = Wo; dst = Wob; off = i - 1835008;
      }
      float4 v = ((const float4*)src)[off];
      ushort4 o;
      o.x = f2bf(v.x); o.y = f2bf(v.y); o.z = f2bf(v.z); o.w = f2bf(v.w);
      ((ushort4*)dst)[off] = o;
    }
  }

  grid_barrier(ctr1, 768u, t);

  // ---- phase 2: QKV gemm (R19 body verbatim) ----
  ushort_t* As0 = smem;
  ushort_t* Bs0 = smem + 4096;
  ushort_t* As1 = smem + 8192;
  ushort_t* Bs1 = smem + 12288;
  const int w = t >> 6, lane = t & 63, quad = lane >> 4, lr = lane & 15;
  const int k8 = bid & 7, u = bid >> 3;  // u in [0,96)
  const int m0 = ((k8 >> 1) * 8 + (u & 7)) * 128;   // m-tile in [0,32)
  const int n0 = ((k8 & 1) * 12 + (u >> 3)) * 128;  // n-tile in [0,24)
  const int wm = (w & 1) * 64, wn = (w >> 1) * 64;
  const int matid = n0 >> 10;
  const int nl0 = n0 & 1023;

  const int srow4 = t >> 2;
  const int gsrc4 = (t & 3) ^ ((t >> 3) & 3);
  const ushort_t* Ag0 = Xbf + (size_t)(m0 + srow4) * E_DIM + gsrc4 * 8;
  const ushort_t* Ag1 = Xbf + (size_t)(m0 + 64 + srow4) * E_DIM + gsrc4 * 8;
  const ushort_t* Bg0 = Wqkv + (size_t)matid * E_DIM * E_DIM +
                        (size_t)(nl0 + srow4) * E_DIM + gsrc4 * 8;
  const ushort_t* Bg1 = Wqkv + (size_t)matid * E_DIM * E_DIM +
                        (size_t)(nl0 + 64 + srow4) * E_DIM + gsrc4 * 8;

  f32x4 acc[4][4] = {};

  GLDS16(Ag0, As0 + t * 8);
  GLDS16(Ag1, As0 + 2048 + t * 8);
  GLDS16(Bg0, Bs0 + t * 8);
  GLDS16(Bg1, Bs0 + 2048 + t * 8);
  __syncthreads();

  for (int kt = 0; kt < E_DIM / 32; kt += 2) {
    GQ_STEP(kt, As0, Bs0, As1, Bs1, 1);
    GQ_STEP(kt + 1, As1, Bs1, As0, Bs0, (kt < E_DIM / 32 - 2));
  }

  const float* bias_p = (matid == 0) ? bq : (matid == 1) ? bk : bv;
  ushort_t* Ls = smem;
  if (matid < 2) {
    ushort_t* dst = (matid == 0) ? Qb : Kb;
    const float scl = (matid == 0) ? 0.18033688f : 1.0f;  // 0.125*log2e
#pragma unroll
    for (int j = 0; j < 4; j++) {
      const int nb = wn + j * 16 + quad * 4;
      float b0 = bias_p[nl0 + nb], b1 = bias_p[nl0 + nb + 1];
      float b2 = bias_p[nl0 + nb + 2], b3 = bias_p[nl0 + nb + 3];
#pragma unroll
      for (int i = 0; i < 4; i++) {
        const int m = wm + i * 16 + lr;
        bf16x4 pv;
        pv[0] = (__bf16)((acc[i][j][0] + b0) * scl);
        pv[1] = (__bf16)((acc[i][j][1] + b1) * scl);
        pv[2] = (__bf16)((acc[i][j][2] + b2) * scl);
        pv[3] = (__bf16)((acc[i][j][3] + b3) * scl);
        *(bf16x4*)(Ls + m * 128 + (((nb >> 3) ^ (m & 7)) * 8) + (nb & 7)) = pv;
      }
    }
    __syncthreads();
#pragma unroll
    for (int it = 0; it < 8; it++) {
      const int task = t + 256 * it;
      const int m = task >> 4, g = task & 15;
      uint4 val = *(const uint4*)(Ls + m * 128 + ((g ^ (m & 7)) * 8));
      const int s = m0 + m, bb = s >> 11, ss = s & 2047;
      const int cl = nl0 + g * 8, h = cl >> 6, dd = cl & 63;
      *(uint4*)(dst + ((size_t)((bb * H_NUM + h) * S_LEN + ss)) * HD_DIM + dd) =
          val;
    }
  } else {
#pragma unroll
    for (int j = 0; j < 4; j++) {
      const int n = wn + j * 16 + lr;
      const float bias = bias_p[nl0 + n];
#pragma unroll
      for (int i = 0; i < 4; i++) {
        const int mb = wm + i * 16 + quad * 4;
        bf16x4 pv;
        pv[0] = (__bf16)(acc[i][j][0] + bias);
        pv[1] = (__bf16)(acc[i][j][1] + bias);
        pv[2] = (__bf16)(acc[i][j][2] + bias);
        pv[3] = (__bf16)(acc[i][j][3] + bias);
        *(bf16x4*)(Ls + n * 128 + (((mb >> 3) ^ (n & 7)) * 8) + (mb & 7)) = pv;
      }
    }
    __syncthreads();
    const int n = t & 127, grp2 = t >> 7;
    ushort_t v[64];
#pragma unroll
    for (int c = 0; c < 8; c++)
      *(uint4*)(v + c * 8) =
          *(const uint4*)(Ls + n * 128 + (((grp2 * 8 + c) ^ (n & 7)) * 8));
    const int cl = nl0 + n, h = cl >> 6, dd = cl & 63;
    const int sgb = m0 + grp2 * 64, bb = sgb >> 11, ssb = sgb & 2047;
    ushort_t* dstp =
        Vt + ((size_t)((bb * H_NUM + h) * HD_DIM + dd)) * S_LEN + ssb;
#pragma unroll
    for (int q = 0; q < 8; q++) {
      ushort_t o8[8];
#pragma unroll
      for (int u2 = 0; u2 < 8; u2++)
        o8[u2] = v[16 * (u2 & 3) + 2 * q + (u2 >> 2)];
      *(uint4*)(dstp + q * 8) = *(const uint4*)o8;
    }
  }
}

// ---------------- fused flash attention + output gemm ----------------------
// Phase 1: R14 attn verbatim (8 waves, dbuf K/V, 1 barrier/tile).
// Phase 2 (after barrier): gemm_out 128x64 tiles at 512 threads: 8 waves of
// 32x32 (wm=(w&3)*32, wn=(w>>2)*32, acc[2][2]); 2-phase dbuf; same swizzles.

#define ATTN_STEP(KT, Kc, Vc, Kn, Vn)                                         \
  {                                                                           \
    const int kn = ((KT) + 1) & (S_LEN / 64 - 1);                             \
    GLDS16(Kg + (size_t)(kn * 64 + srow) * HD_DIM + gsrc * 8, (Kn) + t * 8);  \
    GLDS16(Vg + (size_t)srow * S_LEN + kn * 64 + gsrc * 8, (Vn) + t * 8);     \
    f32x4 sacc[4] = {};                                                       \
    __builtin_amdgcn_s_setprio(1);                                            \
    _Pragma("unroll") for (int nt = 0; nt < 4; nt++) {                        \
      _Pragma("unroll") for (int kc = 0; kc < 2; kc++) {                      \
        const int gs = (kc * 4 + quad) ^ (lr & 7);                            \
        bf16x8 kf = *(const bf16x8*)((Kc) + (nt * 16 + lr) * 64 + gs * 8);    \
        sacc[nt] = __builtin_amdgcn_mfma_f32_16x16x32_bf16(                   \
            qf[kc], kf, sacc[nt], 0, 0, 0);                                   \
      }                                                                       \
    }                                                                         \
    __builtin_amdgcn_s_setprio(0);                                            \
    _Pragma("unroll") for (int i = 0; i < 4; i++) {                           \
      float p0 = EXP2(sacc[0][i]);                                            \
      float p1 = EXP2(sacc[1][i]);                                            \
      float p2 = EXP2(sacc[2][i]);                                            \
      float p3 = EXP2(sacc[3][i]);                                            \
      bf16x4 pv;                                                              \
      pv[0] = (__bf16)p0; pv[1] = (__bf16)p1;                                 \
      pv[2] = (__bf16)p2; pv[3] = (__bf16)p3;                                 \
      const int prow = w * 16 + quad * 4 + i;                                 \
      *(bf16x4*)(Ps + prow * 72 + lr * 4) = pv;                               \
    }                                                                         \
    __builtin_amdgcn_s_setprio(1);                                            \
    _Pragma("unroll") for (int kc = 0; kc < 2; kc++) {                        \
      const int gs = (kc * 4 + quad) ^ (lr & 7);                              \
      bf16x8 vf[4];                                                           \
      _Pragma("unroll") for (int dt = 0; dt < 4; dt++)                        \
        vf[dt] = *(const bf16x8*)((Vc) + (dt * 16 + lr) * 64 + gs * 8);       \
      bf16x8 pf = *(const bf16x8*)(Ps + (w * 16 + lr) * 72 +                  \
                                   kc * 32 + quad * 8);                       \
      lsum = __builtin_amdgcn_mfma_f32_16x16x32_bf16(                         \
          pf, ones, lsum, 0, 0, 0);                                           \
      _Pragma("unroll") for (int dt = 0; dt < 4; dt++)                        \
        cacc[dt] = __builtin_amdgcn_mfma_f32_16x16x32_bf16(                   \
            pf, vf[dt], cacc[dt], 0, 0, 0);                                   \
    }                                                                         \
    __builtin_amdgcn_s_setprio(0);                                            \
    __syncthreads();                                                          \
  }

#define GO_STEP(KT, Ac, Bc, An, Bn, DOPRE)                                    \
  {                                                                           \
    if (DOPRE) {                                                              \
      _Pragma("unroll") for (int r = 0; r < 2; r++)                           \
        GLDS16(Agb + (size_t)((KT) + 1) * 64 + (size_t)r * 64 * E_DIM,        \
               (An) + r * 4096 + t * 8);                                      \
      GLDS16(Bgb + (size_t)((KT) + 1) * 64, (Bn) + t * 8);                    \
    }                                                                         \
    _Pragma("unroll") for (int kk = 0; kk < 2; kk++) {                        \
      bf16x8 af[2], bfr[2];                                                   \
      const int gs0 = (kk * 4 + quad) ^ (lr & 7);                             \
      _Pragma("unroll") for (int i = 0; i < 2; i++)                           \
        af[i]  = *(const bf16x8*)((Ac) + (wm + i * 16 + lr) * 64 + gs0 * 8);  \
      _Pragma("unroll") for (int j = 0; j < 2; j++)                           \
        bfr[j] = *(const bf16x8*)((Bc) + (wn + j * 16 + lr) * 64 + gs0 * 8);  \
      _Pragma("unroll") for (int i = 0; i < 2; i++)                           \
        _Pragma("unroll") for (int j = 0; j < 2; j++)                         \
          acc[i][j] = __builtin_amdgcn_mfma_f32_16x16x32_bf16(                \
              af[i], bfr[j], acc[i][j], 0, 0, 0);                             \
    }                                                                         \
    __syncthreads();                                                          \
  }

__global__ __launch_bounds__(512, 4) void attn_out(
    const ushort_t* __restrict__ Qb, const ushort_t* __restrict__ Kb,
    const ushort_t* __restrict__ Vt, ushort_t* __restrict__ Ctx,
    const ushort_t* __restrict__ Wob, const float* __restrict__ bo,
    float* __restrict__ out, unsigned* __restrict__ ctr2) {
  __shared__ ushort_t smem[25600];  // 50KB; attn carve, reused by out phase
  const int t = threadIdx.x, w = t >> 6, lane = t & 63;
  const int quad = lane >> 4, lr = lane & 15;
  const int bid = blockIdx.x;

  // ---- phase 1: attn (R14 verbatim; Ks/Vs/Ps carved from smem) ----
  {
    ushort_t* Ks0 = smem;             // 4096 ushorts
    ushort_t* Ks1 = smem + 4096;
    ushort_t* Vs0 = smem + 8192;
    ushort_t* Vs1 = smem + 12288;
    ushort_t* Ps  = smem + 16384;     // 9216 ushorts (128 x 72)

    const int bh = (bid >> 7) * 8 + (bid & 7);     // [0,32)
    const int q0 = ((bid >> 3) & 15) * 128;
    const ushort_t* Qg = Qb + ((size_t)bh * S_LEN + q0) * HD_DIM;
    const ushort_t* Kg = Kb + (size_t)bh * S_LEN * HD_DIM;
    const ushort_t* Vg = Vt + (size_t)bh * HD_DIM * S_LEN;

    const int srow = t >> 3;                // staging LDS row in [0,64)
    const int gsrc = (t & 7) ^ (srow & 7);  // swizzled source granule

#pragma unroll
    for (int r = 0; r < 2; r++)
      GLDS16(Qg + (size_t)(r * 64 + srow) * HD_DIM + gsrc * 8,
             Ps + r * 4096 + t * 8);
    GLDS16(Kg + (size_t)srow * HD_DIM + gsrc * 8, Ks0 + t * 8);
    GLDS16(Vg + (size_t)srow * S_LEN + gsrc * 8, Vs0 + t * 8);
    __syncthreads();
    bf16x8 qf[2];  // [kc]; wave-private rows [16w, 16w+16)
#pragma unroll
    for (int kc = 0; kc < 2; kc++) {
      int gs = (kc * 4 + quad) ^ (lr & 7);
      qf[kc] = *(const bf16x8*)(Ps + (w * 16 + lr) * 64 + gs * 8);
    }
    __syncthreads();  // all waves own qf before Ps reused for P rows

    bf16x8 ones;
#pragma unroll
    for (int e = 0; e < 8; e++) ones[e] = (__bf16)1.0f;

    f32x4 cacc[4] = {};
    f32x4 lsum = {};

    for (int kt = 0; kt < S_LEN / 64; kt += 2) {
      ATTN_STEP(kt, Ks0, Vs0, Ks1, Vs1);
      ATTN_STEP(kt + 1, Ks1, Vs1, Ks0, Vs0);
    }

#pragma unroll
    for (int i = 0; i < 4; i++) {
      float inv = 1.0f / lsum[i];
      int srow2 = q0 + w * 16 + quad * 4 + i;
#pragma unroll
      for (int dt = 0; dt < 4; dt++)
        Ctx[((size_t)bh * S_LEN + srow2) * HD_DIM + dt * 16 + lr] =
            f2bf(cacc[dt][i] * inv);
    }
  }

  grid_barrier(ctr2, 512u, t);

  // ---- phase 2: output gemm, 128x64 tiles, 512 threads, 2-phase dbuf ----
  {
    ushort_t* As0 = smem;             // 8192 ushorts (128x64)
    ushort_t* Bs0 = smem + 8192;      // 4096 ushorts (64x64)
    ushort_t* As1 = smem + 12288;
    ushort_t* Bs1 = smem + 20480;     // ends 24576 <= 25600

    const int k8 = bid & 7, u = bid >> 3;     // u in [0,64)
    const int m0 = (k8 * 4 + (u & 3)) * 128;  // m-tile in [0,32)
    const int n0 = (u >> 2) * 64;             // n-tile in [0,16)
    const int wm = (w & 3) * 32, wn = (w >> 2) * 32;  // 8 waves: 4m x 2n

    const int srow = t >> 3;                // [0,64): 64-row staging chunks
    const int gsrc = (t & 7) ^ (srow & 7);
    const ushort_t* Agb =
        (const ushort_t*)Ctx + (size_t)(m0 + srow) * E_DIM + gsrc * 8;
    const ushort_t* Bgb = Wob + (size_t)(n0 + srow) * E_DIM + gsrc * 8;

    f32x4 acc[2][2] = {};

    // prologue: stage kt=0 into buf0 (A: 2 passes of 64 rows; B: 1 pass)
#pragma unroll
    for (int r = 0; r < 2; r++)
      GLDS16(Agb + (size_t)r * 64 * E_DIM, As0 + r * 4096 + t * 8);
    GLDS16(Bgb, Bs0 + t * 8);
    __syncthreads();

    for (int kt = 0; kt < E_DIM / 64; kt += 2) {
      GO_STEP(kt, As0, Bs0, As1, Bs1, 1);
      GO_STEP(kt + 1, As1, Bs1, As0, Bs0, (kt < E_DIM / 64 - 2));
    }

    // acc[i][j]: row m = wm+i*16+quad*4+r, col n = wn+j*16+lr.
#pragma unroll
    for (int j = 0; j < 2; j++) {
      const int col = n0 + wn + j * 16 + lr;
      const float bias = bo[col];
#pragma unroll
      for (int i = 0; i < 2; i++) {
#pragma unroll
        for (int r = 0; r < 4; r++) {
          const int row = m0 + wm + i * 16 + quad * 4 + r;
          out[(size_t)row * E_DIM + col] = acc[i][j][r] + bias;
        }
      }
    }
  }
}

// ---------------- launch ----------------
extern "C" void kernel_launch(void* const* d_in, const int* in_sizes, int n_in,
                              void* d_out, int out_size, void* d_ws,
                              size_t ws_size, hipStream_t stream) {
  const float* X  = (const float*)d_in[0];
  const float* bq = (const float*)d_in[2];
  const float* bk = (const float*)d_in[4];
  const float* bv = (const float*)d_in[6];
  const float* Wo = (const float*)d_in[7];
  const float* bo = (const float*)d_in[8];
  float* out = (float*)d_out;

  char* ws = (char*)d_ws;
  ushort_t* Xbf  = (ushort_t*)(ws);                       // 8 MB
  ushort_t* Wqkv = (ushort_t*)(ws + ((size_t)8 << 20));   // 6 MB
  ushort_t* Wob  = (ushort_t*)(ws + ((size_t)14 << 20));  // 2 MB
  ushort_t* Qb   = (ushort_t*)(ws + ((size_t)16 << 20));  // 8 MB
  ushort_t* Kb   = (ushort_t*)(ws + ((size_t)24 << 20));  // 8 MB
  ushort_t* Vt   = (ushort_t*)(ws + ((size_t)32 << 20));  // 8 MB
  ushort_t* Cb   = (ushort_t*)(ws + ((size_t)40 << 20));  // 8 MB (48 MB total)

  // Barrier counters alias memory written only AFTER their barrier:
  // ctr1 = Cb[0:4) (attn overwrites Cb in the next kernel);
  // ctr2 = out[0:4) (out-phase writes out only after all blocks arrive;
  // spinners poll every ~2us and exit within one poll of count==512, long
  // before any block's 20us gemm epilogue can overwrite the word).
  unsigned* ctr1 = (unsigned*)Cb;
  unsigned* ctr2 = (unsigned*)out;
  hipMemsetAsync(ctr1, 0, 4, stream);
  hipMemsetAsync(ctr2, 0, 4, stream);

  cvt_qkv<<<768, 256, 0, stream>>>(X, (const float*)d_in[1],
                                   (const float*)d_in[3],
                                   (const float*)d_in[5], Wo, Xbf, Wqkv, Wob,
                                   bq, bk, bv, Qb, Kb, Vt, ctr1);
  attn_out<<<512, 512, 0, stream>>>(Qb, Kb, Vt, Cb, Wob, bo, out, ctr2);
}

// Round 12
// 178.939 us; speedup vs baseline: 3.4770x; 3.3390x over previous
//
#include <hip/hip_runtime.h>

// ---------------------------------------------------------------------------
// multi_head_attention: B=2, S=2048, E=1024, H=16, HD=64, fp32 in/out.
// bf16 MFMA (16x16x32) everywhere, fp32 accumulate.
// R1-R11: swizzles, permuted-key P/V, fused cvt, XCD-locality block swizzles
//     (K/V L2-resident, FETCH 12.3MB).
// R12-R15: attn ladder -> R14 best: 512-thr blocks, 16 q-rows/wave, 8 waves,
//     K/V dbuf, ONE barrier/kv-tile, 47.5us. R13 lesson: only
//     global_load_lds+barrier survives hipcc scheduling.
// R16-R19: gemm restructures: R17 (2-phase dbuf staging both gemms) was the
//     only win: 190->181.5. R18 (gemm_out 128x64@512blk) and R19 (qkv BK=32
//     @3blk/CU) flat within noise.
// R20/R21: persistent-kernel fusion with grid barriers: REGRESSED 622/597us
//     under two different barrier protocols (acquire-per-poll, then
//     relaxed-spin + single fences). Counters show normal work and normal
//     memory traffic but ~220us/kernel of counter-invisible waiting ->
//     the persistent structure itself (staggered per-block wbL2/inv fences,
//     exact-capacity co-residency) is the cost. Line abandoned per
//     pre-commitment.
// R22: REVERT to R17 exactly (session best, 181.5us measured at Round 7).
// ---------------------------------------------------------------------------

typedef __bf16 bf16x8 __attribute__((ext_vector_type(8)));
typedef __bf16 bf16x4 __attribute__((ext_vector_type(4)));
typedef float f32x4 __attribute__((ext_vector_type(4)));
typedef unsigned short ushort_t;

#define S_LEN 2048
#define E_DIM 1024
#define H_NUM 16
#define HD_DIM 64

#if __has_builtin(__builtin_amdgcn_exp2f)
#define EXP2(x) __builtin_amdgcn_exp2f(x)
#else
#define EXP2(x) __exp2f(x)
#endif

__device__ __forceinline__ ushort_t f2bf(float f) {
  union { float f; unsigned u; } v; v.f = f;
  unsigned u = v.u;
  unsigned r = (u + 0x7FFFu + ((u >> 16) & 1u)) >> 16;  // RNE
  return (ushort_t)r;
}

#define GLDS16(gp, lp)                                              \
  __builtin_amdgcn_global_load_lds(                                 \
      (const __attribute__((address_space(1))) unsigned int*)(gp),  \
      (__attribute__((address_space(3))) unsigned int*)(lp), 16, 0, 0)

// ---------------- fused fp32 -> bf16 converts (one kernel) ----------------
__global__ __launch_bounds__(256) void cvt_all(
    const float* __restrict__ X, const float* __restrict__ Wq,
    const float* __restrict__ Wk, const float* __restrict__ Wv,
    const float* __restrict__ Wo, ushort_t* __restrict__ Xbf,
    ushort_t* __restrict__ Wqkv, ushort_t* __restrict__ Wob) {
  int i = blockIdx.x * 256 + threadIdx.x;
  const float* src;
  ushort_t* dst;
  int off;
  if (i < 1048576) {
    src = X; dst = Xbf; off = i;
  } else if (i < 1310720) {
    src = Wq; dst = Wqkv; off = i - 1048576;
  } else if (i < 1572864) {
    src = Wk; dst = Wqkv + (1 << 20); off = i - 1310720;
  } else if (i < 1835008) {
    src = Wv; dst = Wqkv + (2 << 20); off = i - 1572864;
  } else {
    src = Wo; dst = Wob; off = i - 1835008;
  }
  float4 v = ((const float4*)src)[off];
  ushort4 o;
  o.x = f2bf(v.x); o.y = f2bf(v.y); o.z = f2bf(v.z); o.w = f2bf(v.w);
  ((ushort4*)dst)[off] = o;
}

// ---------------- fused QKV projection gemm (BK=64, 2-phase dbuf) ----------
// A = Xbf [4096][1024], B = Wqkv [3][1024][1024] (row = out col, k contig)
// grid: 768 blocks 1D. XCD swizzle: xcd k owns an 8m x 12n super-block.
// {prefetch kt+1 -> other buf; compute kt; barrier} - one barrier/kt.

#define GQ_STEP(KT, Ac, Bc, An, Bn, DOPRE)                                    \
  {                                                                           \
    if (DOPRE) {                                                              \
      _Pragma("unroll") for (int r = 0; r < 4; r++) {                         \
        GLDS16(Agb + (size_t)((KT) + 1) * 64 + (size_t)r * 32 * E_DIM,        \
               (An) + r * 2048 + t * 8);                                      \
        GLDS16(Bgb + (size_t)((KT) + 1) * 64 + (size_t)r * 32 * E_DIM,        \
               (Bn) + r * 2048 + t * 8);                                      \
      }                                                                       \
    }                                                                         \
    _Pragma("unroll") for (int kk = 0; kk < 2; kk++) {                        \
      bf16x8 af[4], bfr[4];                                                   \
      const int gs0 = (kk * 4 + quad) ^ (lr & 7);                             \
      _Pragma("unroll") for (int i = 0; i < 4; i++) {                         \
        af[i]  = *(const bf16x8*)((Ac) + (wm + i * 16 + lr) * 64 + gs0 * 8);  \
        bfr[i] = *(const bf16x8*)((Bc) + (wn + i * 16 + lr) * 64 + gs0 * 8);  \
      }                                                                       \
      if (matid < 2) {                                                        \
        _Pragma("unroll") for (int i = 0; i < 4; i++)                         \
          _Pragma("unroll") for (int j = 0; j < 4; j++)                       \
            acc[i][j] = __builtin_amdgcn_mfma_f32_16x16x32_bf16(              \
                bfr[j], af[i], acc[i][j], 0, 0, 0); /* C^T */                 \
      } else {                                                                \
        _Pragma("unroll") for (int i = 0; i < 4; i++)                         \
          _Pragma("unroll") for (int j = 0; j < 4; j++)                       \
            acc[i][j] = __builtin_amdgcn_mfma_f32_16x16x32_bf16(              \
                af[i], bfr[j], acc[i][j], 0, 0, 0);                           \
      }                                                                       \
    }                                                                         \
    __syncthreads();                                                          \
  }

__global__ __launch_bounds__(256) void gemm_qkv(
    const ushort_t* __restrict__ Xbf, const ushort_t* __restrict__ Wqkv,
    const float* __restrict__ bq, const float* __restrict__ bk,
    const float* __restrict__ bv,
    ushort_t* __restrict__ Qb, ushort_t* __restrict__ Kb,
    ushort_t* __restrict__ Vt) {
  __shared__ ushort_t smem[32768];  // 2x(As|Bs); reused as 128x128 C tile
  ushort_t* As0 = smem;
  ushort_t* Bs0 = smem + 8192;
  ushort_t* As1 = smem + 16384;
  ushort_t* Bs1 = smem + 24576;
  const int t = threadIdx.x;
  const int w = t >> 6, lane = t & 63, quad = lane >> 4, lr = lane & 15;
  const int bid = blockIdx.x;
  const int k8 = bid & 7, u = bid >> 3;  // u in [0,96)
  const int m0 = ((k8 >> 1) * 8 + (u & 7)) * 128;   // m-tile in [0,32)
  const int n0 = ((k8 & 1) * 12 + (u >> 3)) * 128;  // n-tile in [0,24)
  const int wm = (w & 1) * 64, wn = (w >> 1) * 64;
  const int matid = n0 >> 10;
  const int nl0 = n0 & 1023;

  const int srow = t >> 3;
  const int gsrc = (t & 7) ^ (srow & 7);
  const ushort_t* Agb = Xbf + (size_t)(m0 + srow) * E_DIM + gsrc * 8;
  const ushort_t* Bgb = Wqkv + (size_t)matid * E_DIM * E_DIM +
                        (size_t)(nl0 + srow) * E_DIM + gsrc * 8;

  f32x4 acc[4][4] = {};

  // prologue: stage kt=0 into buf0
#pragma unroll
  for (int r = 0; r < 4; r++) {
    GLDS16(Agb + (size_t)r * 32 * E_DIM, As0 + r * 2048 + t * 8);
    GLDS16(Bgb + (size_t)r * 32 * E_DIM, Bs0 + r * 2048 + t * 8);
  }
  __syncthreads();

  for (int kt = 0; kt < E_DIM / 64; kt += 2) {
    GQ_STEP(kt, As0, Bs0, As1, Bs1, 1);
    GQ_STEP(kt + 1, As1, Bs1, As0, Bs0, (kt < E_DIM / 64 - 2));
  }

  const float* bias_p = (matid == 0) ? bq : (matid == 1) ? bk : bv;
  ushort_t* Ls = smem;
  if (matid < 2) {
    // acc[i][j] = C^T tile: row n = wn+j*16+quad*4+r, col m = wm+i*16+lr.
    ushort_t* dst = (matid == 0) ? Qb : Kb;
    const float scl = (matid == 0) ? 0.18033688f : 1.0f;  // 0.125*log2e
#pragma unroll
    for (int j = 0; j < 4; j++) {
      const int nb = wn + j * 16 + quad * 4;
      float b0 = bias_p[nl0 + nb], b1 = bias_p[nl0 + nb + 1];
      float b2 = bias_p[nl0 + nb + 2], b3 = bias_p[nl0 + nb + 3];
#pragma unroll
      for (int i = 0; i < 4; i++) {
        const int m = wm + i * 16 + lr;
        bf16x4 pv;
        pv[0] = (__bf16)((acc[i][j][0] + b0) * scl);
        pv[1] = (__bf16)((acc[i][j][1] + b1) * scl);
        pv[2] = (__bf16)((acc[i][j][2] + b2) * scl);
        pv[3] = (__bf16)((acc[i][j][3] + b3) * scl);
        *(bf16x4*)(Ls + m * 128 + (((nb >> 3) ^ (m & 7)) * 8) + (nb & 7)) = pv;
      }
    }
    __syncthreads();
#pragma unroll
    for (int it = 0; it < 8; it++) {
      const int task = t + 256 * it;
      const int m = task >> 4, g = task & 15;
      uint4 val = *(const uint4*)(Ls + m * 128 + ((g ^ (m & 7)) * 8));
      const int s = m0 + m, bb = s >> 11, ss = s & 2047;
      const int cl = nl0 + g * 8, h = cl >> 6, dd = cl & 63;
      *(uint4*)(dst + ((size_t)((bb * H_NUM + h) * S_LEN + ss)) * HD_DIM + dd) =
          val;
    }
  } else {
    // acc[i][j] = C tile: row m(s), col n(d). Stage Ls[n][m], b64 along m.
#pragma unroll
    for (int j = 0; j < 4; j++) {
      const int n = wn + j * 16 + lr;
      const float bias = bias_p[nl0 + n];
#pragma unroll
      for (int i = 0; i < 4; i++) {
        const int mb = wm + i * 16 + quad * 4;
        bf16x4 pv;
        pv[0] = (__bf16)(acc[i][j][0] + bias);
        pv[1] = (__bf16)(acc[i][j][1] + bias);
        pv[2] = (__bf16)(acc[i][j][2] + bias);
        pv[3] = (__bf16)(acc[i][j][3] + bias);
        *(bf16x4*)(Ls + n * 128 + (((mb >> 3) ^ (n & 7)) * 8) + (mb & 7)) = pv;
      }
    }
    __syncthreads();
    const int n = t & 127, grp2 = t >> 7;
    ushort_t v[64];
#pragma unroll
    for (int c = 0; c < 8; c++)
      *(uint4*)(v + c * 8) =
          *(const uint4*)(Ls + n * 128 + (((grp2 * 8 + c) ^ (n & 7)) * 8));
    const int cl = nl0 + n, h = cl >> 6, dd = cl & 63;
    const int sgb = m0 + grp2 * 64, bb = sgb >> 11, ssb = sgb & 2047;
    ushort_t* dstp =
        Vt + ((size_t)((bb * H_NUM + h) * HD_DIM + dd)) * S_LEN + ssb;
#pragma unroll
    for (int q = 0; q < 8; q++) {
      ushort_t o8[8];
#pragma unroll
      for (int u2 = 0; u2 < 8; u2++)
        o8[u2] = v[16 * (u2 & 3) + 2 * q + (u2 >> 2)];
      *(uint4*)(dstp + q * 8) = *(const uint4*)o8;
    }
  }
}

// ---------------- flash attention (q-tile 128, 16 q-rows/wave, 8 waves) ----
// grid: 512 blocks x 512 threads. XCD swizzle: bid = bh%8 + 8*q + 128*(bh/8)
// so all 16 q-tiles of a bh share one XCD (K/V 2MB/XCD -> L2-resident).
// R14 (best): K/V double-buffered, prefetch at top, ONE barrier per kv-tile.

// One kv-tile step. Kc/Vc: buffers being consumed; Kn/Vn: prefetch targets.
#define ATTN_STEP(KT, Kc, Vc, Kn, Vn)                                         \
  {                                                                           \
    const int kn = ((KT) + 1) & (S_LEN / 64 - 1);                             \
    GLDS16(Kg + (size_t)(kn * 64 + srow) * HD_DIM + gsrc * 8, (Kn) + t * 8);  \
    GLDS16(Vg + (size_t)srow * S_LEN + kn * 64 + gsrc * 8, (Vn) + t * 8);     \
    f32x4 sacc[4] = {};                                                       \
    __builtin_amdgcn_s_setprio(1);                                            \
    _Pragma("unroll") for (int nt = 0; nt < 4; nt++) {                        \
      _Pragma("unroll") for (int kc = 0; kc < 2; kc++) {                      \
        const int gs = (kc * 4 + quad) ^ (lr & 7);                            \
        bf16x8 kf = *(const bf16x8*)((Kc) + (nt * 16 + lr) * 64 + gs * 8);    \
        sacc[nt] = __builtin_amdgcn_mfma_f32_16x16x32_bf16(                   \
            qf[kc], kf, sacc[nt], 0, 0, 0);                                   \
      }                                                                       \
    }                                                                         \
    __builtin_amdgcn_s_setprio(0);                                            \
    _Pragma("unroll") for (int i = 0; i < 4; i++) {                           \
      float p0 = EXP2(sacc[0][i]);                                            \
      float p1 = EXP2(sacc[1][i]);                                            \
      float p2 = EXP2(sacc[2][i]);                                            \
      float p3 = EXP2(sacc[3][i]);                                            \
      bf16x4 pv;                                                              \
      pv[0] = (__bf16)p0; pv[1] = (__bf16)p1;                                 \
      pv[2] = (__bf16)p2; pv[3] = (__bf16)p3;                                 \
      const int prow = w * 16 + quad * 4 + i;                                 \
      *(bf16x4*)(Ps + prow * 72 + lr * 4) = pv;                               \
    }                                                                         \
    __builtin_amdgcn_s_setprio(1);                                            \
    _Pragma("unroll") for (int kc = 0; kc < 2; kc++) {                        \
      const int gs = (kc * 4 + quad) ^ (lr & 7);                              \
      bf16x8 vf[4];                                                           \
      _Pragma("unroll") for (int dt = 0; dt < 4; dt++)                        \
        vf[dt] = *(const bf16x8*)((Vc) + (dt * 16 + lr) * 64 + gs * 8);       \
      bf16x8 pf = *(const bf16x8*)(Ps + (w * 16 + lr) * 72 +                  \
                                   kc * 32 + quad * 8);                       \
      lsum = __builtin_amdgcn_mfma_f32_16x16x32_bf16(                         \
          pf, ones, lsum, 0, 0, 0);                                           \
      _Pragma("unroll") for (int dt = 0; dt < 4; dt++)                        \
        cacc[dt] = __builtin_amdgcn_mfma_f32_16x16x32_bf16(                   \
            pf, vf[dt], cacc[dt], 0, 0, 0);                                   \
    }                                                                         \
    __builtin_amdgcn_s_setprio(0);                                            \
    __syncthreads(); /* vmcnt(0) drain: prefetch had the WHOLE iter to land */\
  }

__global__ __launch_bounds__(512) void attn(
    const ushort_t* __restrict__ Qb, const ushort_t* __restrict__ Kb,
    const ushort_t* __restrict__ Vt, ushort_t* __restrict__ Ctx) {
  __shared__ ushort_t Ks[2][64 * 64];  // double-buffered swizzled K tiles
  __shared__ ushort_t Vs[2][64 * 64];  // double-buffered swizzled V^T tiles
  __shared__ ushort_t Ps[128 * 72];    // P rows (stride 72); Q staged flat 1st
  const int t = threadIdx.x, w = t >> 6, lane = t & 63;
  const int quad = lane >> 4, lr = lane & 15;
  const int bid = blockIdx.x;
  const int bh = (bid >> 7) * 8 + (bid & 7);     // [0,32)
  const int q0 = ((bid >> 3) & 15) * 128;
  const ushort_t* Qg = Qb + ((size_t)bh * S_LEN + q0) * HD_DIM;
  const ushort_t* Kg = Kb + (size_t)bh * S_LEN * HD_DIM;
  const ushort_t* Vg = Vt + (size_t)bh * HD_DIM * S_LEN;

  const int srow = t >> 3;                // staging LDS row in [0,64)
  const int gsrc = (t & 7) ^ (srow & 7);  // swizzled source granule

  // prologue: stage Q (flat into Ps, 128x64), K tile 0, V tile 0 into buf 0
#pragma unroll
  for (int r = 0; r < 2; r++)
    GLDS16(Qg + (size_t)(r * 64 + srow) * HD_DIM + gsrc * 8,
           Ps + r * 4096 + t * 8);
  GLDS16(Kg + (size_t)srow * HD_DIM + gsrc * 8, Ks[0] + t * 8);
  GLDS16(Vg + (size_t)srow * S_LEN + gsrc * 8, Vs[0] + t * 8);
  __syncthreads();
  bf16x8 qf[2];  // [kc]; wave-private rows [16w, 16w+16)
#pragma unroll
  for (int kc = 0; kc < 2; kc++) {
    int gs = (kc * 4 + quad) ^ (lr & 7);
    qf[kc] = *(const bf16x8*)(Ps + (w * 16 + lr) * 64 + gs * 8);
  }
  // Ps is reused for P rows (stride 72) which overlaps OTHER waves' Q rows
  // (stride 64) -> all waves must own qf before any P write.
  __syncthreads();

  bf16x8 ones;
#pragma unroll
  for (int e = 0; e < 8; e++) ones[e] = (__bf16)1.0f;

  f32x4 cacc[4] = {};
  f32x4 lsum = {};

  for (int kt = 0; kt < S_LEN / 64; kt += 2) {
    ATTN_STEP(kt, Ks[0], Vs[0], Ks[1], Vs[1]);
    ATTN_STEP(kt + 1, Ks[1], Vs[1], Ks[0], Vs[0]);
  }

  // epilogue: lsum holds full row sums (identical across the 16 lanes)
#pragma unroll
  for (int i = 0; i < 4; i++) {
    float inv = 1.0f / lsum[i];
    int srow2 = q0 + w * 16 + quad * 4 + i;
#pragma unroll
    for (int dt = 0; dt < 4; dt++)
      Ctx[((size_t)bh * S_LEN + srow2) * HD_DIM + dt * 16 + lr] =
          f2bf(cacc[dt][i] * inv);
  }
}

// ---------------- output projection gemm (128x128 tiles, 2-phase dbuf) ------
// A = Cb [4096][1024], B = Wob [1024][1024] (row = out col, k contig).
// grid: 256 blocks 1D. XCD swizzle: xcd k owns m-tiles [4k,4k+4) x all 8 n
// (A 1MB + Wo 2MB per XCD -> L2-resident). One barrier per kt.

#define GO_STEP(KT, Ac, Bc, An, Bn, DOPRE)                                    \
  {                                                                           \
    if (DOPRE) {                                                              \
      _Pragma("unroll") for (int r = 0; r < 4; r++) {                         \
        GLDS16(Agb + (size_t)((KT) + 1) * 64 + (size_t)r * 32 * E_DIM,        \
               (An) + r * 2048 + t * 8);                                      \
        GLDS16(Bgb + (size_t)((KT) + 1) * 64 + (size_t)r * 32 * E_DIM,        \
               (Bn) + r * 2048 + t * 8);                                      \
      }                                                                       \
    }                                                                         \
    _Pragma("unroll") for (int kk = 0; kk < 2; kk++) {                        \
      bf16x8 af[4], bfr[4];                                                   \
      const int gs0 = (kk * 4 + quad) ^ (lr & 7);                             \
      _Pragma("unroll") for (int i = 0; i < 4; i++) {                         \
        af[i]  = *(const bf16x8*)((Ac) + (wm + i * 16 + lr) * 64 + gs0 * 8);  \
        bfr[i] = *(const bf16x8*)((Bc) + (wn + i * 16 + lr) * 64 + gs0 * 8);  \
      }                                                                       \
      _Pragma("unroll") for (int i = 0; i < 4; i++)                           \
        _Pragma("unroll") for (int j = 0; j < 4; j++)                         \
          acc[i][j] = __builtin_amdgcn_mfma_f32_16x16x32_bf16(                \
              af[i], bfr[j], acc[i][j], 0, 0, 0);                             \
    }                                                                         \
    __syncthreads();                                                          \
  }

__global__ __launch_bounds__(256) void gemm_out(
    const ushort_t* __restrict__ Cb, const ushort_t* __restrict__ Wob,
    const float* __restrict__ bo, float* __restrict__ out) {
  __shared__ ushort_t smem[32768];
  ushort_t* As0 = smem;
  ushort_t* Bs0 = smem + 8192;
  ushort_t* As1 = smem + 16384;
  ushort_t* Bs1 = smem + 24576;
  const int t = threadIdx.x;
  const int w = t >> 6, lane = t & 63, quad = lane >> 4, lr = lane & 15;
  const int bid = blockIdx.x;
  const int k8 = bid & 7, u = bid >> 3;     // u in [0,32)
  const int m0 = (k8 * 4 + (u & 3)) * 128;  // m-tile in [0,32)
  const int n0 = (u >> 2) * 128;            // n-tile in [0,8)
  const int wm = (w & 1) * 64, wn = (w >> 1) * 64;

  const int srow = t >> 3;                // [0,32): 32-row staging chunks
  const int gsrc = (t & 7) ^ (srow & 7);
  const ushort_t* Agb = Cb + (size_t)(m0 + srow) * E_DIM + gsrc * 8;
  const ushort_t* Bgb = Wob + (size_t)(n0 + srow) * E_DIM + gsrc * 8;

  f32x4 acc[4][4] = {};

  // prologue: stage kt=0 into buf0
#pragma unroll
  for (int r = 0; r < 4; r++) {
    GLDS16(Agb + (size_t)r * 32 * E_DIM, As0 + r * 2048 + t * 8);
    GLDS16(Bgb + (size_t)r * 32 * E_DIM, Bs0 + r * 2048 + t * 8);
  }
  __syncthreads();

  for (int kt = 0; kt < E_DIM / 64; kt += 2) {
    GO_STEP(kt, As0, Bs0, As1, Bs1, 1);
    GO_STEP(kt + 1, As1, Bs1, As0, Bs0, (kt < E_DIM / 64 - 2));
  }

  // acc[i][j] = C tile: row m = wm+i*16+quad*4+r, col n = wn+j*16+lr.
#pragma unroll
  for (int j = 0; j < 4; j++) {
    const int col = n0 + wn + j * 16 + lr;
    const float bias = bo[col];
#pragma unroll
    for (int i = 0; i < 4; i++) {
#pragma unroll
      for (int r = 0; r < 4; r++) {
        const int row = m0 + wm + i * 16 + quad * 4 + r;
        out[(size_t)row * E_DIM + col] = acc[i][j][r] + bias;
      }
    }
  }
}

// ---------------- launch ----------------
extern "C" void kernel_launch(void* const* d_in, const int* in_sizes, int n_in,
                              void* d_out, int out_size, void* d_ws,
                              size_t ws_size, hipStream_t stream) {
  const float* X  = (const float*)d_in[0];
  const float* bq = (const float*)d_in[2];
  const float* bk = (const float*)d_in[4];
  const float* bv = (const float*)d_in[6];
  const float* Wo = (const float*)d_in[7];
  const float* bo = (const float*)d_in[8];
  float* out = (float*)d_out;

  char* ws = (char*)d_ws;
  ushort_t* Xbf  = (ushort_t*)(ws);                       // 8 MB
  ushort_t* Wqkv = (ushort_t*)(ws + ((size_t)8 << 20));   // 6 MB
  ushort_t* Wob  = (ushort_t*)(ws + ((size_t)14 << 20));  // 2 MB
  ushort_t* Qb   = (ushort_t*)(ws + ((size_t)16 << 20));  // 8 MB
  ushort_t* Kb   = (ushort_t*)(ws + ((size_t)24 << 20));  // 8 MB
  ushort_t* Vt   = (ushort_t*)(ws + ((size_t)32 << 20));  // 8 MB
  ushort_t* Cb   = (ushort_t*)(ws + ((size_t)40 << 20));  // 8 MB (48 MB total)

  cvt_all<<<8192, 256, 0, stream>>>(X, (const float*)d_in[1],
                                    (const float*)d_in[3],
                                    (const float*)d_in[5], Wo, Xbf, Wqkv, Wob);

  gemm_qkv<<<768, 256, 0, stream>>>(Xbf, Wqkv, bq, bk, bv, Qb, Kb, Vt);
  attn<<<512, 512, 0, stream>>>(Qb, Kb, Vt, Cb);
  gemm_out<<<256, 256, 0, stream>>>(Cb, Wob, bo, out);
}